// Round 9
// baseline (381.496 us; speedup 1.0000x reference)
//
#include <hip/hip_runtime.h>

typedef unsigned int uint;
typedef unsigned short ushort;
typedef __attribute__((ext_vector_type(8))) short bf16x8;
typedef __attribute__((ext_vector_type(4))) float f32x4;

#define NN 100000
#define NE 800000
#define D_IN 256
#define D_HID 128
#define D_OUT 64

// RNE fp32->bf16
__device__ __forceinline__ ushort f2bf(float f) {
    uint u = __float_as_uint(f);
    return (ushort)((u + 0x7fffu + ((u >> 16) & 1u)) >> 16);
}
__device__ __forceinline__ float bflo(uint u) { return __uint_as_float(u << 16); }
__device__ __forceinline__ float bfhi(uint u) { return __uint_as_float(u & 0xffff0000u); }
__device__ __forceinline__ uint pack2(float lo, float hi) {
    return (uint)f2bf(lo) | ((uint)f2bf(hi) << 16);
}
__device__ __forceinline__ bf16x8 pack8(float4 a, float4 b) {
    bf16x8 r;
    r[0] = (short)f2bf(a.x); r[1] = (short)f2bf(a.y); r[2] = (short)f2bf(a.z); r[3] = (short)f2bf(a.w);
    r[4] = (short)f2bf(b.x); r[5] = (short)f2bf(b.y); r[6] = (short)f2bf(b.z); r[7] = (short)f2bf(b.w);
    return r;
}

// ---------------- degree count ----------------
__global__ __launch_bounds__(256) void k_count(const int* __restrict__ dst, int* __restrict__ count, int e) {
    int i = blockIdx.x * 256 + threadIdx.x;
    if (i < e) {
        unsigned d = (unsigned)dst[i];
        if (d < NN) atomicAdd(&count[d], 1);
    }
}

// ---------------- scan stage 1 ----------------
#define SCAN_B 1024
__global__ __launch_bounds__(SCAN_B) void k_scan1(const int* __restrict__ count, int* __restrict__ incl,
                                                  int* __restrict__ blocksum, int n) {
    __shared__ int tmp[SCAN_B];
    int t = threadIdx.x;
    int gid = blockIdx.x * SCAN_B + t;
    int v = (gid < n) ? count[gid] : 0;
    tmp[t] = v;
    __syncthreads();
    for (int off = 1; off < SCAN_B; off <<= 1) {
        int u = (t >= off) ? tmp[t - off] : 0;
        __syncthreads();
        tmp[t] += u;
        __syncthreads();
    }
    if (gid < n) incl[gid] = tmp[t];
    if (t == SCAN_B - 1) blocksum[blockIdx.x] = tmp[t];
}

// ---------------- scan stage 2 (merged): finalize offsets/cursor/dinv ----------------
__global__ __launch_bounds__(256) void k_scan3(const int* __restrict__ incl, const int* __restrict__ count,
                                               const int* __restrict__ blocksum, int nb, int* __restrict__ offsets,
                                               int* __restrict__ cursor, float* __restrict__ dinv, int n) {
    __shared__ int bs[128];
    int t = threadIdx.x;
    if (t < 128) bs[t] = (t < nb) ? blocksum[t] : 0;
    __syncthreads();
    int i = blockIdx.x * 256 + t;
    if (i < n) {
        int b = i >> 10;
        int off = 0;
        for (int j = 0; j < b; j++) off += bs[j];
        int inc = incl[i] + off;
        int exc = inc - count[i];
        offsets[i] = exc;
        cursor[i] = exc;
        dinv[i] = rsqrtf((float)(count[i] + 1));  // +1 self-loop
        if (i == n - 1) offsets[n] = inc;
    }
}

// ---------------- scatter edges into CSC order ----------------
__global__ __launch_bounds__(256) void k_scatter(const int* __restrict__ edges, int* __restrict__ cursor,
                                                 int* __restrict__ srcs, int e) {
    int i = blockIdx.x * 256 + threadIdx.x;
    if (i < e) {
        unsigned s = (unsigned)edges[i];
        unsigned d = (unsigned)edges[e + i];
        if (s < NN && d < NN) {
            int pos = atomicAdd(&cursor[d], 1);
            srcs[pos] = (int)s;
        }
    }
}

// ---------------- both weights: W[K][N] fp32 -> WT[N][K] bf16 ----------------
__global__ __launch_bounds__(256) void k_castW(const float* __restrict__ W1, const float* __restrict__ W2,
                                               ushort* __restrict__ w1t, ushort* __restrict__ w2t) {
    int t = blockIdx.x * 256 + threadIdx.x;
    if (t < D_IN * D_HID) {
        int n = t / D_IN, k = t % D_IN;
        w1t[t] = f2bf(W1[(size_t)k * D_HID + n]);
    } else {
        int u = t - D_IN * D_HID;
        if (u < D_HID * D_OUT) {
            int n = u / D_HID, k = u % D_HID;
            w2t[u] = f2bf(W2[(size_t)k * D_OUT + n]);
        }
    }
}

// ---------------- async-staged MFMA GEMM ----------------
// C[M,N] = (A[M,K] @ B[K,N]) * dinv[row], bf16 out. BT = B^T [N][K] bf16.
// 256 thr = 4 waves. Each wave owns an N-slice of 16*NFW cols and ALL BR block rows.
// A-tile staged whole into LDS via global_load_lds (linear dest, XOR-swizzled SOURCE,
// XOR-swizzled reads -> ~2-way max bank aliasing). B fragments held in registers.
template <int K_DIM, int N_DIM, bool AF32, int MT>
__global__ __launch_bounds__(256) void k_gemm_stage(const void* __restrict__ Av, const ushort* __restrict__ BT,
                                                    const float* __restrict__ dinv, ushort* __restrict__ C, int M) {
    constexpr int NFW = N_DIM / 64;             // N-frags per wave (4 waves cover N)
    constexpr int KK = K_DIM / 32;
    constexpr int BR = MT * 16;                 // block rows
    constexpr int RB = K_DIM * (AF32 ? 4 : 2);  // bytes per A row
    constexpr int LDSB = BR * RB;
    constexpr int CH = LDSB / 16;               // 16B chunks
    __shared__ char lds[LDSB];

    const int tid = threadIdx.x;
    const int w = tid >> 6, lane = tid & 63;
    const int l15 = lane & 15, g = lane >> 4;   // g in 0..3
    const int row0 = blockIdx.x * BR;
    const int cb = w * 16 * NFW;                // wave's first output col

    // B fragments -> registers (BT row-major [N][K], L2/L3-hot, reused across all rows)
    bf16x8 bf[NFW][KK];
#pragma unroll
    for (int nf = 0; nf < NFW; nf++)
#pragma unroll
        for (int kk = 0; kk < KK; kk++)
            bf[nf][kk] = *reinterpret_cast<const bf16x8*>(
                BT + (size_t)(cb + nf * 16 + l15) * K_DIM + kk * 32 + g * 8);

    // stage A-tile: LDS linear dest, global source pre-swizzled with f=(row&7)<<4
    {
        const char* Ab = (const char*)Av;
#pragma unroll
        for (int i = 0; i < CH / 256; i++) {
            int c = (i * 4 + w) * 64 + lane;     // wave-issue covers 1KB contiguous LDS
            int p = c * 16;
            int r = p / RB;
            int off = p & (RB - 1);
            int f = (r & 7) << 4;
            int grow = min(row0 + r, M - 1);     // clamp: no OOB global reads on last block
            const char* src = Ab + (size_t)grow * RB + (off ^ f);
            __builtin_amdgcn_global_load_lds((const __attribute__((address_space(1))) void*)src,
                                             (__attribute__((address_space(3))) void*)(lds + p), 16, 0, 0);
        }
    }
    __syncthreads();  // compiler drains vmcnt here

    f32x4 acc[MT][NFW];
#pragma unroll
    for (int mt = 0; mt < MT; mt++)
#pragma unroll
        for (int nf = 0; nf < NFW; nf++) acc[mt][nf] = (f32x4){0.f, 0.f, 0.f, 0.f};

#pragma unroll
    for (int kk = 0; kk < KK; kk++) {
#pragma unroll
        for (int mt = 0; mt < MT; mt++) {
            const int r = mt * 16 + l15;
            const int f = (r & 7) << 4;
            bf16x8 a;
            if constexpr (AF32) {
                const int o = kk * 128 + g * 32;
                float4 v0 = *(const float4*)(lds + r * RB + (o ^ f));
                float4 v1 = *(const float4*)(lds + r * RB + ((o + 16) ^ f));
                a = pack8(v0, v1);
            } else {
                const int o = kk * 64 + g * 16;
                a = *(const bf16x8*)(lds + r * RB + (o ^ f));
            }
#pragma unroll
            for (int nf = 0; nf < NFW; nf++)
                acc[mt][nf] = __builtin_amdgcn_mfma_f32_16x16x32_bf16(a, bf[nf][kk], acc[mt][nf], 0, 0, 0);
        }
    }

    // D layout: row_in_tile = g*4 + r, col = l15  [learn_hip m89/m91]
#pragma unroll
    for (int mt = 0; mt < MT; mt++) {
#pragma unroll
        for (int r4 = 0; r4 < 4; r4++) {
            int rr = row0 + mt * 16 + g * 4 + r4;
            if (rr < M) {
                float dv = dinv[rr];
#pragma unroll
                for (int nf = 0; nf < NFW; nf++)
                    C[(size_t)rr * N_DIM + cb + nf * 16 + l15] = f2bf(acc[mt][nf][r4] * dv);
            }
        }
    }
}

// ---------------- pull aggregation, F=128 bf16 rows (256B), 16B/lane, 4 rows/wave-load ----------------
__global__ __launch_bounds__(256) void k_agg128(const ushort* __restrict__ hws, const int* __restrict__ srcs,
                                                const int* __restrict__ offs, const float* __restrict__ dinv,
                                                const float* __restrict__ bias, ushort* __restrict__ outb, int n) {
    const int wv = threadIdx.x >> 6, lane = threadIdx.x & 63;
    const int node = blockIdx.x * 4 + wv;
    if (node >= n) return;
    const int g = lane >> 4, l15 = lane & 15;
    const int beg = offs[node];
    const int T = offs[node + 1] - beg + 1;  // items: 0 = self, t>=1 -> srcs[beg+t-1]
    const uint4* base = (const uint4*)hws;   // row = 16 uint4
    float acc[8] = {};
    int t = g;
    for (; t + 4 < T; t += 8) {
        int s0 = (t == 0) ? node : srcs[beg + t - 1];
        int s1 = srcs[beg + t + 3];
        uint4 va = base[(size_t)s0 * 16 + l15];
        uint4 vb = base[(size_t)s1 * 16 + l15];
        acc[0] += bflo(va.x) + bflo(vb.x); acc[1] += bfhi(va.x) + bfhi(vb.x);
        acc[2] += bflo(va.y) + bflo(vb.y); acc[3] += bfhi(va.y) + bfhi(vb.y);
        acc[4] += bflo(va.z) + bflo(vb.z); acc[5] += bfhi(va.z) + bfhi(vb.z);
        acc[6] += bflo(va.w) + bflo(vb.w); acc[7] += bfhi(va.w) + bfhi(vb.w);
    }
    for (; t < T; t += 4) {
        int s0 = (t == 0) ? node : srcs[beg + t - 1];
        uint4 va = base[(size_t)s0 * 16 + l15];
        acc[0] += bflo(va.x); acc[1] += bfhi(va.x);
        acc[2] += bflo(va.y); acc[3] += bfhi(va.y);
        acc[4] += bflo(va.z); acc[5] += bfhi(va.z);
        acc[6] += bflo(va.w); acc[7] += bfhi(va.w);
    }
#pragma unroll
    for (int j = 0; j < 8; j++) {
        acc[j] += __shfl_xor(acc[j], 16);
        acc[j] += __shfl_xor(acc[j], 32);
    }
    if (g == 0) {
        const float dv = dinv[node];
        const float4* b4 = (const float4*)(bias + 8 * l15);
        float4 bb0 = b4[0], bb1 = b4[1];
        uint4 o;
        o.x = pack2(fmaxf(acc[0] * dv + bb0.x, 0.f), fmaxf(acc[1] * dv + bb0.y, 0.f));
        o.y = pack2(fmaxf(acc[2] * dv + bb0.z, 0.f), fmaxf(acc[3] * dv + bb0.w, 0.f));
        o.z = pack2(fmaxf(acc[4] * dv + bb1.x, 0.f), fmaxf(acc[5] * dv + bb1.y, 0.f));
        o.w = pack2(fmaxf(acc[6] * dv + bb1.z, 0.f), fmaxf(acc[7] * dv + bb1.w, 0.f));
        ((uint4*)outb)[(size_t)node * 16 + l15] = o;
    }
}

// ---------------- pull aggregation, F=64 bf16 rows (128B), 16B/lane, fp32 out ----------------
__global__ __launch_bounds__(256) void k_agg64(const ushort* __restrict__ hws, const int* __restrict__ srcs,
                                               const int* __restrict__ offs, const float* __restrict__ dinv,
                                               const float* __restrict__ bias, float* __restrict__ out, int n) {
    const int wv = threadIdx.x >> 6, lane = threadIdx.x & 63;
    const int node = blockIdx.x * 4 + wv;
    if (node >= n) return;
    const int g = lane >> 3, l7 = lane & 7;
    const int beg = offs[node];
    const int T = offs[node + 1] - beg + 1;
    const uint4* base = (const uint4*)hws;  // row = 8 uint4
    float acc[8] = {};
    int t = g;
    for (; t + 8 < T; t += 16) {
        int s0 = (t == 0) ? node : srcs[beg + t - 1];
        int s1 = srcs[beg + t + 7];
        uint4 va = base[(size_t)s0 * 8 + l7];
        uint4 vb = base[(size_t)s1 * 8 + l7];
        acc[0] += bflo(va.x) + bflo(vb.x); acc[1] += bfhi(va.x) + bfhi(vb.x);
        acc[2] += bflo(va.y) + bflo(vb.y); acc[3] += bfhi(va.y) + bfhi(vb.y);
        acc[4] += bflo(va.z) + bflo(vb.z); acc[5] += bfhi(va.z) + bfhi(vb.z);
        acc[6] += bflo(va.w) + bflo(vb.w); acc[7] += bfhi(va.w) + bfhi(vb.w);
    }
    for (; t < T; t += 8) {
        int s0 = (t == 0) ? node : srcs[beg + t - 1];
        uint4 va = base[(size_t)s0 * 8 + l7];
        acc[0] += bflo(va.x); acc[1] += bfhi(va.x);
        acc[2] += bflo(va.y); acc[3] += bfhi(va.y);
        acc[4] += bflo(va.z); acc[5] += bfhi(va.z);
        acc[6] += bflo(va.w); acc[7] += bfhi(va.w);
    }
#pragma unroll
    for (int j = 0; j < 8; j++) {
        acc[j] += __shfl_xor(acc[j], 8);
        acc[j] += __shfl_xor(acc[j], 16);
        acc[j] += __shfl_xor(acc[j], 32);
    }
    if (g == 0) {
        const float dv = dinv[node];
        const float4* b4 = (const float4*)(bias + 8 * l7);
        float4 bb0 = b4[0], bb1 = b4[1];
        float4 o0, o1;
        o0.x = acc[0] * dv + bb0.x; o0.y = acc[1] * dv + bb0.y;
        o0.z = acc[2] * dv + bb0.z; o0.w = acc[3] * dv + bb0.w;
        o1.x = acc[4] * dv + bb1.x; o1.y = acc[5] * dv + bb1.y;
        o1.z = acc[6] * dv + bb1.z; o1.w = acc[7] * dv + bb1.w;
        ((float4*)out)[(size_t)node * 16 + 2 * l7] = o0;
        ((float4*)out)[(size_t)node * 16 + 2 * l7 + 1] = o1;
    }
}

static inline size_t align_up(size_t x, size_t a) { return (x + a - 1) & ~(a - 1); }

extern "C" void kernel_launch(void* const* d_in, const int* in_sizes, int n_in,
                              void* d_out, int out_size, void* d_ws, size_t ws_size,
                              hipStream_t stream) {
    const float* x = (const float*)d_in[0];
    const int* edges = (const int*)d_in[1];  // int32 per harness integer convention
    const float* W1 = (const float*)d_in[2];
    const float* b1 = (const float*)d_in[3];
    const float* W2 = (const float*)d_in[4];
    const float* b2 = (const float*)d_in[5];
    float* out = (float*)d_out;

    char* p = (char*)d_ws;
    int* count = (int*)p;      p += align_up(NN * 4, 256);
    int* incl = (int*)p;       p += align_up(NN * 4, 256);
    int* offsets = (int*)p;    p += align_up((NN + 1) * 4, 256);
    int* cursor = (int*)p;     p += align_up(NN * 4, 256);
    int* srcs = (int*)p;       p += align_up(NE * 4, 256);
    int* blocksum = (int*)p;   p += align_up(256 * 4, 256);
    float* dinv = (float*)p;   p += align_up(NN * 4, 256);
    ushort* w1t = (ushort*)p;  p += align_up(D_IN * D_HID * 2, 256);
    ushort* w2t = (ushort*)p;  p += align_up(D_HID * D_OUT * 2, 256);
    ushort* hw1s = (ushort*)p; p += align_up((size_t)NN * D_HID * 2, 256);
    ushort* hb = (ushort*)p;   p += align_up((size_t)NN * D_HID * 2 + 32 * 1024, 256);  // +pad: clamped OOB-tail reads
    ushort* hw2s = (ushort*)p; p += align_up((size_t)NN * D_OUT * 2, 256);

    const int nb_scan = (NN + SCAN_B - 1) / SCAN_B;  // 98

    hipMemsetAsync(count, 0, NN * 4, stream);
    k_count<<<(NE + 255) / 256, 256, 0, stream>>>(edges + NE, count, NE);
    k_scan1<<<nb_scan, SCAN_B, 0, stream>>>(count, incl, blocksum, NN);
    k_scan3<<<(NN + 255) / 256, 256, 0, stream>>>(incl, count, blocksum, nb_scan, offsets, cursor, dinv, NN);
    k_scatter<<<(NE + 255) / 256, 256, 0, stream>>>(edges, cursor, srcs, NE);
    k_castW<<<(D_IN * D_HID + D_HID * D_OUT + 255) / 256, 256, 0, stream>>>(W1, W2, w1t, w2t);

    // layer 1: hw1s = (x @ W1) * dinv  (fp32 A staged async, fused cast; B in regs)
    k_gemm_stage<D_IN, D_HID, true, 4><<<(NN + 63) / 64, 256, 0, stream>>>(x, w1t, dinv, hw1s, NN);
    k_agg128<<<(NN + 3) / 4, 256, 0, stream>>>(hw1s, srcs, offsets, dinv, b1, hb, NN);

    // layer 2: hw2s = (h @ W2) * dinv
    k_gemm_stage<D_HID, D_OUT, false, 8><<<(NN + 127) / 128, 256, 0, stream>>>(hb, w2t, dinv, hw2s, NN);
    k_agg64<<<(NN + 3) / 4, 256, 0, stream>>>(hw2s, srcs, offsets, dinv, b2, out, NN);
}

// Round 10
// 371.537 us; speedup vs baseline: 1.0268x; 1.0268x over previous
//
#include <hip/hip_runtime.h>

typedef unsigned int uint;
typedef unsigned short ushort;
typedef __attribute__((ext_vector_type(8))) short bf16x8;
typedef __attribute__((ext_vector_type(4))) float f32x4;

#define NN 100000
#define NE 800000
#define D_IN 256
#define D_HID 128
#define D_OUT 64

// RNE fp32->bf16
__device__ __forceinline__ ushort f2bf(float f) {
    uint u = __float_as_uint(f);
    return (ushort)((u + 0x7fffu + ((u >> 16) & 1u)) >> 16);
}
__device__ __forceinline__ float bflo(uint u) { return __uint_as_float(u << 16); }
__device__ __forceinline__ float bfhi(uint u) { return __uint_as_float(u & 0xffff0000u); }
__device__ __forceinline__ uint pack2(float lo, float hi) {
    return (uint)f2bf(lo) | ((uint)f2bf(hi) << 16);
}
__device__ __forceinline__ bf16x8 pack8(float4 a, float4 b) {
    bf16x8 r;
    r[0] = (short)f2bf(a.x); r[1] = (short)f2bf(a.y); r[2] = (short)f2bf(a.z); r[3] = (short)f2bf(a.w);
    r[4] = (short)f2bf(b.x); r[5] = (short)f2bf(b.y); r[6] = (short)f2bf(b.z); r[7] = (short)f2bf(b.w);
    return r;
}

// ---------------- degree count ----------------
__global__ __launch_bounds__(256) void k_count(const int* __restrict__ dst, int* __restrict__ count, int e) {
    int i = blockIdx.x * 256 + threadIdx.x;
    if (i < e) {
        unsigned d = (unsigned)dst[i];
        if (d < NN) atomicAdd(&count[d], 1);
    }
}

// ---------------- scan stage 1 ----------------
#define SCAN_B 1024
__global__ __launch_bounds__(SCAN_B) void k_scan1(const int* __restrict__ count, int* __restrict__ incl,
                                                  int* __restrict__ blocksum, int n) {
    __shared__ int tmp[SCAN_B];
    int t = threadIdx.x;
    int gid = blockIdx.x * SCAN_B + t;
    int v = (gid < n) ? count[gid] : 0;
    tmp[t] = v;
    __syncthreads();
    for (int off = 1; off < SCAN_B; off <<= 1) {
        int u = (t >= off) ? tmp[t - off] : 0;
        __syncthreads();
        tmp[t] += u;
        __syncthreads();
    }
    if (gid < n) incl[gid] = tmp[t];
    if (t == SCAN_B - 1) blocksum[blockIdx.x] = tmp[t];
}

// ---------------- scan stage 2 (merged): finalize offsets/cursor/dinv ----------------
__global__ __launch_bounds__(256) void k_scan3(const int* __restrict__ incl, const int* __restrict__ count,
                                               const int* __restrict__ blocksum, int nb, int* __restrict__ offsets,
                                               int* __restrict__ cursor, float* __restrict__ dinv, int n) {
    __shared__ int bs[128];
    int t = threadIdx.x;
    if (t < 128) bs[t] = (t < nb) ? blocksum[t] : 0;
    __syncthreads();
    int i = blockIdx.x * 256 + t;
    if (i < n) {
        int b = i >> 10;
        int off = 0;
        for (int j = 0; j < b; j++) off += bs[j];
        int inc = incl[i] + off;
        int exc = inc - count[i];
        offsets[i] = exc;
        cursor[i] = exc;
        dinv[i] = rsqrtf((float)(count[i] + 1));  // +1 self-loop
        if (i == n - 1) offsets[n] = inc;
    }
}

// ---------------- scatter edges into CSC order ----------------
__global__ __launch_bounds__(256) void k_scatter(const int* __restrict__ edges, int* __restrict__ cursor,
                                                 int* __restrict__ srcs, int e) {
    int i = blockIdx.x * 256 + threadIdx.x;
    if (i < e) {
        unsigned s = (unsigned)edges[i];
        unsigned d = (unsigned)edges[e + i];
        if (s < NN && d < NN) {
            int pos = atomicAdd(&cursor[d], 1);
            srcs[pos] = (int)s;
        }
    }
}

// ---------------- both weights: W[K][N] fp32 -> WT[N][K] bf16 ----------------
__global__ __launch_bounds__(256) void k_castW(const float* __restrict__ W1, const float* __restrict__ W2,
                                               ushort* __restrict__ w1t, ushort* __restrict__ w2t) {
    int t = blockIdx.x * 256 + threadIdx.x;
    if (t < D_IN * D_HID) {
        int n = t / D_IN, k = t % D_IN;
        w1t[t] = f2bf(W1[(size_t)k * D_HID + n]);
    } else {
        int u = t - D_IN * D_HID;
        if (u < D_HID * D_OUT) {
            int n = u / D_HID, k = u % D_HID;
            w2t[u] = f2bf(W2[(size_t)k * D_OUT + n]);
        }
    }
}

// ---------------- double-buffered MFMA GEMM ----------------
// C[M,N] = (A[M,K] @ B[K,N]) * dinv[row], bf16 out. BT = B^T [N][K] bf16.
// WAVES waves; wave w owns cols [w*16, w*16+16) -> B-frags in registers (KK*4 VGPR).
// A staged to LDS in 16-row halves via global_load_lds, double-buffered:
// issue stage(next) BEFORE compute(cur); one __syncthreads per half (2-phase recipe).
// XOR source-pre-swizzle f=(r&7)<<4, same XOR on LDS reads (rule 21).
template <int K_DIM, int N_DIM, bool AF32, int WAVES, int NH>
__global__ __launch_bounds__(WAVES * 64) void k_gemm_db(const void* __restrict__ Av, const ushort* __restrict__ BT,
                                                        const float* __restrict__ dinv, ushort* __restrict__ C,
                                                        int M) {
    constexpr int THREADS = WAVES * 64;
    constexpr int KK = K_DIM / 32;
    constexpr int RB = K_DIM * (AF32 ? 4 : 2);  // bytes per A row
    constexpr int HB = 16 * RB;                 // bytes per 16-row half
    constexpr int CPT = HB / 16 / THREADS;      // 16B chunks per thread per half
    constexpr int BR = NH * 16;                 // rows per block
    __shared__ char lds[2 * HB];

    const int tid = threadIdx.x;
    const int w = tid >> 6, lane = tid & 63;
    const int l15 = lane & 15, g = lane >> 4;  // g in 0..3
    const int row0 = blockIdx.x * BR;
    const int colw = w * 16;

    // B fragments -> registers (KK frags = KK*4 VGPR; small, no spill)
    bf16x8 bf[KK];
#pragma unroll
    for (int kk = 0; kk < KK; kk++)
        bf[kk] = *reinterpret_cast<const bf16x8*>(BT + (size_t)(colw + l15) * K_DIM + kk * 32 + g * 8);

    const char* Ab = (const char*)Av;
    const int fme = (l15 & 7) << 4;

    auto stage = [&](char* buf, int h) {
#pragma unroll
        for (int i = 0; i < CPT; i++) {
            int c = i * THREADS + tid;
            int p = c * 16;
            int r = p / RB;
            int off = p - r * RB;
            int f = (r & 7) << 4;
            int grow = min(row0 + h * 16 + r, M - 1);
            const char* src = Ab + (size_t)grow * RB + (off ^ f);
            __builtin_amdgcn_global_load_lds((const __attribute__((address_space(1))) void*)src,
                                             (__attribute__((address_space(3))) void*)(buf + p), 16, 0, 0);
        }
    };

    auto compute = [&](const char* buf, int h) {
        f32x4 acc = (f32x4){0.f, 0.f, 0.f, 0.f};
#pragma unroll
        for (int kk = 0; kk < KK; kk++) {
            bf16x8 a;
            if constexpr (AF32) {
                const int o = kk * 128 + g * 32;
                float4 v0 = *(const float4*)(buf + l15 * RB + (o ^ fme));
                float4 v1 = *(const float4*)(buf + l15 * RB + ((o + 16) ^ fme));
                a = pack8(v0, v1);
            } else {
                const int o = kk * 64 + g * 16;
                a = *(const bf16x8*)(buf + l15 * RB + (o ^ fme));
            }
            acc = __builtin_amdgcn_mfma_f32_16x16x32_bf16(a, bf[kk], acc, 0, 0, 0);
        }
        // D layout: row_in_tile = g*4 + r4, col = l15  [learn_hip m89/m91]
#pragma unroll
        for (int r4 = 0; r4 < 4; r4++) {
            int rr = row0 + h * 16 + g * 4 + r4;
            if (rr < M) C[(size_t)rr * N_DIM + colw + l15] = f2bf(acc[r4] * dinv[rr]);
        }
    };

    char* b0 = lds;
    char* b1 = lds + HB;
    stage(b0, 0);
    __syncthreads();
#pragma unroll
    for (int h = 0; h < NH; h++) {
        const char* cur = (h & 1) ? b1 : b0;
        char* nxt = (h & 1) ? b0 : b1;
        if (h + 1 < NH) stage(nxt, h + 1);  // in flight during compute(cur)
        compute(cur, h);
        __syncthreads();  // drains next-half loads + buffer handoff
    }
}

// ---------------- pull aggregation, F=128 bf16 rows (256B), 16B/lane, 4 rows/wave-load ----------------
__global__ __launch_bounds__(256) void k_agg128(const ushort* __restrict__ hws, const int* __restrict__ srcs,
                                                const int* __restrict__ offs, const float* __restrict__ dinv,
                                                const float* __restrict__ bias, ushort* __restrict__ outb, int n) {
    const int wv = threadIdx.x >> 6, lane = threadIdx.x & 63;
    const int node = blockIdx.x * 4 + wv;
    if (node >= n) return;
    const int g = lane >> 4, l15 = lane & 15;
    const int beg = offs[node];
    const int T = offs[node + 1] - beg + 1;  // items: 0 = self, t>=1 -> srcs[beg+t-1]
    const uint4* base = (const uint4*)hws;   // row = 16 uint4
    float acc[8] = {};
    int t = g;
    for (; t + 4 < T; t += 8) {
        int s0 = (t == 0) ? node : srcs[beg + t - 1];
        int s1 = srcs[beg + t + 3];
        uint4 va = base[(size_t)s0 * 16 + l15];
        uint4 vb = base[(size_t)s1 * 16 + l15];
        acc[0] += bflo(va.x) + bflo(vb.x); acc[1] += bfhi(va.x) + bfhi(vb.x);
        acc[2] += bflo(va.y) + bflo(vb.y); acc[3] += bfhi(va.y) + bfhi(vb.y);
        acc[4] += bflo(va.z) + bflo(vb.z); acc[5] += bfhi(va.z) + bfhi(vb.z);
        acc[6] += bflo(va.w) + bflo(vb.w); acc[7] += bfhi(va.w) + bfhi(vb.w);
    }
    for (; t < T; t += 4) {
        int s0 = (t == 0) ? node : srcs[beg + t - 1];
        uint4 va = base[(size_t)s0 * 16 + l15];
        acc[0] += bflo(va.x); acc[1] += bfhi(va.x);
        acc[2] += bflo(va.y); acc[3] += bfhi(va.y);
        acc[4] += bflo(va.z); acc[5] += bfhi(va.z);
        acc[6] += bflo(va.w); acc[7] += bfhi(va.w);
    }
#pragma unroll
    for (int j = 0; j < 8; j++) {
        acc[j] += __shfl_xor(acc[j], 16);
        acc[j] += __shfl_xor(acc[j], 32);
    }
    if (g == 0) {
        const float dv = dinv[node];
        const float4* b4 = (const float4*)(bias + 8 * l15);
        float4 bb0 = b4[0], bb1 = b4[1];
        uint4 o;
        o.x = pack2(fmaxf(acc[0] * dv + bb0.x, 0.f), fmaxf(acc[1] * dv + bb0.y, 0.f));
        o.y = pack2(fmaxf(acc[2] * dv + bb0.z, 0.f), fmaxf(acc[3] * dv + bb0.w, 0.f));
        o.z = pack2(fmaxf(acc[4] * dv + bb1.x, 0.f), fmaxf(acc[5] * dv + bb1.y, 0.f));
        o.w = pack2(fmaxf(acc[6] * dv + bb1.z, 0.f), fmaxf(acc[7] * dv + bb1.w, 0.f));
        ((uint4*)outb)[(size_t)node * 16 + l15] = o;
    }
}

// ---------------- pull aggregation, F=64 bf16 rows (128B), 16B/lane, fp32 out ----------------
__global__ __launch_bounds__(256) void k_agg64(const ushort* __restrict__ hws, const int* __restrict__ srcs,
                                               const int* __restrict__ offs, const float* __restrict__ dinv,
                                               const float* __restrict__ bias, float* __restrict__ out, int n) {
    const int wv = threadIdx.x >> 6, lane = threadIdx.x & 63;
    const int node = blockIdx.x * 4 + wv;
    if (node >= n) return;
    const int g = lane >> 3, l7 = lane & 7;
    const int beg = offs[node];
    const int T = offs[node + 1] - beg + 1;
    const uint4* base = (const uint4*)hws;  // row = 8 uint4
    float acc[8] = {};
    int t = g;
    for (; t + 8 < T; t += 16) {
        int s0 = (t == 0) ? node : srcs[beg + t - 1];
        int s1 = srcs[beg + t + 7];
        uint4 va = base[(size_t)s0 * 8 + l7];
        uint4 vb = base[(size_t)s1 * 8 + l7];
        acc[0] += bflo(va.x) + bflo(vb.x); acc[1] += bfhi(va.x) + bfhi(vb.x);
        acc[2] += bflo(va.y) + bflo(vb.y); acc[3] += bfhi(va.y) + bfhi(vb.y);
        acc[4] += bflo(va.z) + bflo(vb.z); acc[5] += bfhi(va.z) + bfhi(vb.z);
        acc[6] += bflo(va.w) + bflo(vb.w); acc[7] += bfhi(va.w) + bfhi(vb.w);
    }
    for (; t < T; t += 8) {
        int s0 = (t == 0) ? node : srcs[beg + t - 1];
        uint4 va = base[(size_t)s0 * 8 + l7];
        acc[0] += bflo(va.x); acc[1] += bfhi(va.x);
        acc[2] += bflo(va.y); acc[3] += bfhi(va.y);
        acc[4] += bflo(va.z); acc[5] += bfhi(va.z);
        acc[6] += bflo(va.w); acc[7] += bfhi(va.w);
    }
#pragma unroll
    for (int j = 0; j < 8; j++) {
        acc[j] += __shfl_xor(acc[j], 8);
        acc[j] += __shfl_xor(acc[j], 16);
        acc[j] += __shfl_xor(acc[j], 32);
    }
    if (g == 0) {
        const float dv = dinv[node];
        const float4* b4 = (const float4*)(bias + 8 * l7);
        float4 bb0 = b4[0], bb1 = b4[1];
        float4 o0, o1;
        o0.x = acc[0] * dv + bb0.x; o0.y = acc[1] * dv + bb0.y;
        o0.z = acc[2] * dv + bb0.z; o0.w = acc[3] * dv + bb0.w;
        o1.x = acc[4] * dv + bb1.x; o1.y = acc[5] * dv + bb1.y;
        o1.z = acc[6] * dv + bb1.z; o1.w = acc[7] * dv + bb1.w;
        ((float4*)out)[(size_t)node * 16 + 2 * l7] = o0;
        ((float4*)out)[(size_t)node * 16 + 2 * l7 + 1] = o1;
    }
}

static inline size_t align_up(size_t x, size_t a) { return (x + a - 1) & ~(a - 1); }

extern "C" void kernel_launch(void* const* d_in, const int* in_sizes, int n_in,
                              void* d_out, int out_size, void* d_ws, size_t ws_size,
                              hipStream_t stream) {
    const float* x = (const float*)d_in[0];
    const int* edges = (const int*)d_in[1];  // int32 per harness integer convention
    const float* W1 = (const float*)d_in[2];
    const float* b1 = (const float*)d_in[3];
    const float* W2 = (const float*)d_in[4];
    const float* b2 = (const float*)d_in[5];
    float* out = (float*)d_out;

    char* p = (char*)d_ws;
    int* count = (int*)p;      p += align_up(NN * 4, 256);
    int* incl = (int*)p;       p += align_up(NN * 4, 256);
    int* offsets = (int*)p;    p += align_up((NN + 1) * 4, 256);
    int* cursor = (int*)p;     p += align_up(NN * 4, 256);
    int* srcs = (int*)p;       p += align_up(NE * 4, 256);
    int* blocksum = (int*)p;   p += align_up(256 * 4, 256);
    float* dinv = (float*)p;   p += align_up(NN * 4, 256);
    ushort* w1t = (ushort*)p;  p += align_up(D_IN * D_HID * 2, 256);
    ushort* w2t = (ushort*)p;  p += align_up(D_HID * D_OUT * 2, 256);
    ushort* hw1s = (ushort*)p; p += align_up((size_t)NN * D_HID * 2, 256);
    ushort* hb = (ushort*)p;   p += align_up((size_t)NN * D_HID * 2 + 32 * 1024, 256);  // +pad (legacy, harmless)
    ushort* hw2s = (ushort*)p; p += align_up((size_t)NN * D_OUT * 2, 256);

    const int nb_scan = (NN + SCAN_B - 1) / SCAN_B;  // 98

    hipMemsetAsync(count, 0, NN * 4, stream);
    k_count<<<(NE + 255) / 256, 256, 0, stream>>>(edges + NE, count, NE);
    k_scan1<<<nb_scan, SCAN_B, 0, stream>>>(count, incl, blocksum, NN);
    k_scan3<<<(NN + 255) / 256, 256, 0, stream>>>(incl, count, blocksum, nb_scan, offsets, cursor, dinv, NN);
    k_scatter<<<(NE + 255) / 256, 256, 0, stream>>>(edges, cursor, srcs, NE);
    k_castW<<<(D_IN * D_HID + D_HID * D_OUT + 255) / 256, 256, 0, stream>>>(W1, W2, w1t, w2t);

    const int gemm_blocks = (NN + 63) / 64;  // 1563 (64 rows/block)

    // layer 1: hw1s = (x @ W1) * dinv  (fp32 A, fused cast; A dbuf-staged; B in regs, 32 VGPR)
    k_gemm_db<D_IN, D_HID, true, 8, 4><<<gemm_blocks, 512, 0, stream>>>(x, w1t, dinv, hw1s, NN);
    k_agg128<<<(NN + 3) / 4, 256, 0, stream>>>(hw1s, srcs, offsets, dinv, b1, hb, NN);

    // layer 2: hw2s = (h @ W2) * dinv  (bf16 A; B in regs, 16 VGPR)
    k_gemm_db<D_HID, D_OUT, false, 4, 4><<<gemm_blocks, 256, 0, stream>>>(hb, w2t, dinv, hw2s, NN);
    k_agg64<<<(NN + 3) / 4, 256, 0, stream>>>(hw2s, srcs, offsets, dinv, b2, out, NN);
}